// Round 1
// baseline (153.231 us; speedup 1.0000x reference)
//
#include <hip/hip_runtime.h>

#define TT 32
#define EMB 256
#define HEAD 64

typedef __attribute__((ext_vector_type(8)))  short  bf16x8;
typedef __attribute__((ext_vector_type(4)))  short  s16x4;
typedef __attribute__((ext_vector_type(16))) float  f32x16;
typedef __attribute__((ext_vector_type(4)))  float  f32x4;

__device__ __forceinline__ short f2bf(float f) {
  unsigned u = __builtin_bit_cast(unsigned, f);
  u += 0x7fffu + ((u >> 16) & 1u);
  return (short)(u >> 16);
}

// Wt[n][k] = W_{n/64}[k][n%64] as bf16; n in [0,192), k in [0,256)
__global__ void prep_weights(const float* __restrict__ Wq,
                             const float* __restrict__ Wk,
                             const float* __restrict__ Wv,
                             short* __restrict__ Wt) {
  int idx = blockIdx.x * 256 + threadIdx.x;   // 192*256 total
  int n = idx >> 8, k = idx & 255;
  const float* W = (n < 64) ? Wq : (n < 128) ? Wk : Wv;
  Wt[n * 256 + k] = f2bf(W[k * 64 + (n & 63)]);
}

__global__ __launch_bounds__(256, 2)
void attn_kernel(const float* __restrict__ X,
                 const short* __restrict__ Wt,
                 const float* __restrict__ bq,
                 const float* __restrict__ bk,
                 const float* __restrict__ bv,
                 float* __restrict__ out) {
  // per-wave private LDS: sQ[32][64] sK[32][64] sVt[64][32] sP[32][32] (bf16)
  __shared__ short smem[4 * 7168];

  const int tid  = threadIdx.x;
  const int wid  = tid >> 6;
  const int lane = tid & 63;
  const int lo   = lane & 31;   // tile row/col index
  const int hi   = lane >> 5;   // k-half selector

  const long b = (long)blockIdx.x * 4 + wid;

  short* sQ  = smem + wid * 7168;
  short* sK  = sQ + 2048;
  short* sVt = sK + 2048;
  short* sP  = sVt + 2048;

  const float* Xb = X + b * (TT * EMB);

  // ---------------- projections: QKV = X @ Wt^T + b ----------------
  f32x16 acc[6];  // p = (proj<<1)|ntile : Q0 Q1 K0 K1 V0 V1
#pragma unroll
  for (int i = 0; i < 6; ++i)
#pragma unroll
    for (int j = 0; j < 16; ++j) acc[i][j] = 0.0f;

#pragma unroll 4
  for (int kk = 0; kk < 16; ++kk) {
    // A fragment: X[row=lo][k = kk*16 + hi*8 + j]
    const float* xp = Xb + lo * EMB + kk * 16 + hi * 8;
    f32x4 x0 = *(const f32x4*)xp;
    f32x4 x1 = *(const f32x4*)(xp + 4);
    bf16x8 a;
    a[0] = f2bf(x0[0]); a[1] = f2bf(x0[1]); a[2] = f2bf(x0[2]); a[3] = f2bf(x0[3]);
    a[4] = f2bf(x1[0]); a[5] = f2bf(x1[1]); a[6] = f2bf(x1[2]); a[7] = f2bf(x1[3]);
#pragma unroll
    for (int p = 0; p < 6; ++p) {
      // B fragment: Wt[n = p*32+lo][k contiguous 8] (16B, L2-resident)
      const short* wp = Wt + (p * 32 + lo) * 256 + kk * 16 + hi * 8;
      bf16x8 bb = *(const bf16x8*)wp;
      acc[p] = __builtin_amdgcn_mfma_f32_32x32x16_bf16(a, bb, acc[p], 0, 0, 0);
    }
  }

  // bias add, convert to bf16, write to LDS (Q,K row-major swizzled; V transposed)
#pragma unroll
  for (int p = 0; p < 6; ++p) {
    const int h = (p & 1) * 32 + lo;                      // C col = lane&31
    const float bias = (p < 2 ? bq : p < 4 ? bk : bv)[h];
    if (p < 4) {
      short* dst = (p < 2) ? sQ : sK;
#pragma unroll
      for (int r = 0; r < 16; ++r) {
        int row = (r & 3) + 8 * (r >> 2) + 4 * hi;        // C row formula
        dst[(row * 64 + h) ^ ((row & 7) << 3)] = f2bf(acc[p][r] + bias);
      }
    } else {
      // Vt[h][s]: regs g*4..g*4+3 are consecutive s -> packed 8B writes
#pragma unroll
      for (int g = 0; g < 4; ++g) {
        int s0 = g * 8 + hi * 4;
        s16x4 v4;
        v4[0] = f2bf(acc[p][g * 4 + 0] + bias);
        v4[1] = f2bf(acc[p][g * 4 + 1] + bias);
        v4[2] = f2bf(acc[p][g * 4 + 2] + bias);
        v4[3] = f2bf(acc[p][g * 4 + 3] + bias);
        *(s16x4*)&sVt[(h * 32 + s0) ^ ((h & 3) << 3)] = v4;
      }
    }
  }

  // ---------------- swapped QK^T: weiT[s][t] = K @ Q^T ----------------
  f32x16 w;
#pragma unroll
  for (int j = 0; j < 16; ++j) w[j] = 0.0f;
#pragma unroll
  for (int kk = 0; kk < 4; ++kk) {
    int k0 = kk * 16 + hi * 8;
    bf16x8 aK = *(bf16x8*)&sK[(lo * 64 + k0) ^ ((lo & 7) << 3)];
    bf16x8 bQ = *(bf16x8*)&sQ[(lo * 64 + k0) ^ ((lo & 7) << 3)];
    w = __builtin_amdgcn_mfma_f32_32x32x16_bf16(aK, bQ, w, 0, 0, 0);
  }

  // ---------------- softmax over s for query t = lo (lane pairs l, l^32) ----
  const int t = lo;
  float pv[16];
  float m = -3.0e38f;
#pragma unroll
  for (int r = 0; r < 16; ++r) {
    int s = (r & 3) + 8 * (r >> 2) + 4 * hi;
    float v = (s <= t) ? w[r] * 0.125f : -__builtin_inff();  // mask then /sqrt(64)
    pv[r] = v;
    m = fmaxf(m, v);
  }
  m = fmaxf(m, __shfl_xor(m, 32));
  float sum = 0.0f;
#pragma unroll
  for (int r = 0; r < 16; ++r) {
    float e = __expf(pv[r] - m);   // exp(-inf)=0 handles the mask
    pv[r] = e;
    sum += e;
  }
  sum += __shfl_xor(sum, 32);
  const float inv = 1.0f / sum;

  // write P[t][s] bf16 (normalized), packed 8B, swizzled
#pragma unroll
  for (int g = 0; g < 4; ++g) {
    int s0 = g * 8 + hi * 4;
    s16x4 v4;
    v4[0] = f2bf(pv[g * 4 + 0] * inv);
    v4[1] = f2bf(pv[g * 4 + 1] * inv);
    v4[2] = f2bf(pv[g * 4 + 2] * inv);
    v4[3] = f2bf(pv[g * 4 + 3] * inv);
    *(s16x4*)&sP[(t * 32 + s0) ^ ((t & 3) << 3)] = v4;
  }

  // ---------------- out = P @ V ----------------
  f32x16 o[2];
#pragma unroll
  for (int i = 0; i < 2; ++i)
#pragma unroll
    for (int j = 0; j < 16; ++j) o[i][j] = 0.0f;

#pragma unroll
  for (int kk = 0; kk < 2; ++kk) {
    int s0 = kk * 16 + hi * 8;
    bf16x8 aP = *(bf16x8*)&sP[(lo * 32 + s0) ^ ((lo & 3) << 3)];
#pragma unroll
    for (int nt = 0; nt < 2; ++nt) {
      int h = nt * 32 + lo;
      bf16x8 bV = *(bf16x8*)&sVt[(h * 32 + s0) ^ ((h & 3) << 3)];
      o[nt] = __builtin_amdgcn_mfma_f32_32x32x16_bf16(aP, bV, o[nt], 0, 0, 0);
    }
  }

  // coalesced fp32 stores
  float* ob = out + b * (TT * HEAD);
#pragma unroll
  for (int nt = 0; nt < 2; ++nt) {
    int h = nt * 32 + lo;
#pragma unroll
    for (int r = 0; r < 16; ++r) {
      int row = (r & 3) + 8 * (r >> 2) + 4 * hi;
      ob[row * HEAD + h] = o[nt][r];
    }
  }
}

extern "C" void kernel_launch(void* const* d_in, const int* in_sizes, int n_in,
                              void* d_out, int out_size, void* d_ws, size_t ws_size,
                              hipStream_t stream) {
  const float* X  = (const float*)d_in[0];
  const float* Wq = (const float*)d_in[1];
  const float* bq = (const float*)d_in[2];
  const float* Wk = (const float*)d_in[3];
  const float* bk = (const float*)d_in[4];
  const float* Wv = (const float*)d_in[5];
  const float* bv = (const float*)d_in[6];
  float* out = (float*)d_out;
  short* Wt = (short*)d_ws;  // 192*256 bf16 = 96 KB scratch

  const int B = in_sizes[0] / (TT * EMB);  // 8192

  prep_weights<<<192, 256, 0, stream>>>(Wq, Wk, Wv, Wt);
  attn_kernel<<<B / 4, 256, 0, stream>>>(X, Wt, bq, bk, bv, out);
}